// Round 15
// baseline (48.574 us; speedup 1.0000x reference)
//
#include <hip/hip_runtime.h>

// Problem constants (resolution = 512 per reference).
#define SCALE   510                // resolution - 2
#define NCELLS  (SCALE * SCALE)    // 260100
#define NF      4
#define PRIME_Y 2654435761u
#define PRIME_Z 805459861u

// Phase A: hash-partition into 32 groups (idx>>14), LDS-staged.
#define NGRP    32
#define NBLKA   512
#define CAPA    320      // per-(block,group) mean 244, +4.9 sigma
#define PAT     1024
#define SEGASTR 321      // +1 pad: bank = (g+r)%32, random g spreads

// Phase B: per-group table slice in LDS + x-bucket binning (r6 format).
#define NBKT    256      // bkt = u>>1 in [0,254]
#define NBLKB   512      // 32 groups x 16 subsets
#define SUBS    16
#define CAPB    72       // mean 30.5 (61 for bkt 254); spill path covers tails
#define PBT     1024
#define LROWB   258      // u16 stride: drain conflict-free, bin spread by bkt

#define PHT     1024
#define SPILLCAP 65536

// Workspace layout (bytes, all 256-aligned by construction):
#define GSEGA_BYTES  ((size_t)NBLKA * NGRP * CAPA * 4)     // 20,971,520
#define RECS_BYTES   ((size_t)NBLKB * NBKT * CAPB * 2)     // 18,874,368
#define CNTA_BYTES   ((size_t)NGRP * NBLKA * 2)            // 32,768
#define CNTG_BYTES   ((size_t)NBKT * NBLKB * 2)            // 262,144
#define SIGN_BYTES   ((size_t)262144)                      // 2^19 nibbles
#define HDR_BYTES    ((size_t)256)
#define SPILLA_BYTES ((size_t)SPILLCAP * 8)
#define SPILLB_BYTES ((size_t)SPILLCAP * 4)

// ---------------------------------------------------------------- signtab ---
// Pack 4 sign bits per hash entry into a nibble (2^19 entries -> 256 KB).
// Also zeroes the two spill counters.
__global__ void signtab_kernel(const float4* __restrict__ emb,
                               unsigned char* __restrict__ signtab,
                               unsigned int* __restrict__ hdr,
                               unsigned int hsize) {
    unsigned int i = blockIdx.x * blockDim.x + threadIdx.x;   // byte index
    if (i < 2) hdr[i] = 0;
    if (i * 2 >= hsize) return;
    float4 e0 = emb[2 * i + 0];
    float4 e1 = emb[2 * i + 1];
    unsigned int b = 0;
    if (e0.x >= 0.0f) b |= 1u << 0;
    if (e0.y >= 0.0f) b |= 1u << 1;
    if (e0.z >= 0.0f) b |= 1u << 2;
    if (e0.w >= 0.0f) b |= 1u << 3;
    if (e1.x >= 0.0f) b |= 1u << 4;
    if (e1.y >= 0.0f) b |= 1u << 5;
    if (e1.z >= 0.0f) b |= 1u << 6;
    if (e1.w >= 0.0f) b |= 1u << 7;
    signtab[i] = (unsigned char)b;
}

// -------------------------------------------------------- phase A: split ----
// Record: (hlow14 << 18) | (u9 << 9) | v9  — exactly 32 bits.
__device__ __forceinline__ void split_point(
        int x, int y, int z,
        unsigned int* __restrict__ segA, unsigned int* __restrict__ rankA,
        unsigned int* __restrict__ spillcnt, unsigned long long* __restrict__ spillA,
        unsigned int hmask) {
    unsigned int h = (unsigned int)x
                   ^ ((unsigned int)y * PRIME_Y)
                   ^ ((unsigned int)z * PRIME_Z);
    unsigned int idx = h & hmask;
    unsigned int g   = idx >> 14;          // 5 bits (hsize == 2^19 guarded)
    unsigned int hl  = idx & 0x3FFFu;      // 14 bits
    unsigned int u = (unsigned int)min(max(x, 0), SCALE - 1);
    unsigned int v = (unsigned int)min(max(y, 0), SCALE - 1);
    unsigned int w = (hl << 18) | (u << 9) | v;
    unsigned int r = atomicAdd(&rankA[g], 1u);              // LDS atomic
    if (r < CAPA) {
        segA[g * SEGASTR + r] = w;                          // LDS write
    } else {                                                // ~0 expected
        unsigned int rs = atomicAdd(spillcnt, 1u);
        if (rs < SPILLCAP)
            spillA[rs] = ((unsigned long long)g << 32) | w;
    }
}

__global__ __launch_bounds__(PAT)
void hashsplit_kernel(const int* __restrict__ inputs,
                      unsigned int* __restrict__ gsegA,
                      unsigned short* __restrict__ cntA,
                      unsigned int* __restrict__ hdr,
                      unsigned long long* __restrict__ spillA,
                      int n, unsigned int hmask) {
    __shared__ unsigned int segA[NGRP * SEGASTR];           // 41,088 B
    __shared__ unsigned int rankA[NGRP];
    const int t = threadIdx.x, b = blockIdx.x;
    if (t < NGRP) rankA[t] = 0;
    __syncthreads();

    const int nquad = n >> 2;
    const int qpb = (nquad + NBLKA - 1) / NBLKA;
    const int q0 = b * qpb;
    const int q1 = min(q0 + qpb, nquad);
    const int4* in4 = (const int4*)inputs;
    for (int q = q0 + t; q < q1; q += PAT) {
        int4 A = in4[3 * q + 0];
        int4 B = in4[3 * q + 1];
        int4 C = in4[3 * q + 2];
        split_point(A.x, A.y, A.z, segA, rankA, hdr, spillA, hmask);
        split_point(A.w, B.x, B.y, segA, rankA, hdr, spillA, hmask);
        split_point(B.z, B.w, C.x, segA, rankA, hdr, spillA, hmask);
        split_point(C.y, C.z, C.w, segA, rankA, hdr, spillA, hmask);
    }
    if (b == 0 && t == 0) {                                 // n%4 tail
        for (int p = nquad * 4; p < n; ++p)
            split_point(inputs[3 * p], inputs[3 * p + 1], inputs[3 * p + 2],
                        segA, rankA, hdr, spillA, hmask);
    }
    __syncthreads();

    // Coalesced drain: [g][r] -> gsegA[b][g][r].
    for (int j = t; j < NGRP * CAPA; j += PAT)
        gsegA[(size_t)b * NGRP * CAPA + j] =
            segA[(j / CAPA) * SEGASTR + (j % CAPA)];
    if (t < NGRP)
        cntA[t * NBLKA + b] = (unsigned short)min(rankA[t], (unsigned int)CAPA);
}

// ------------------------------------------------------ phase B: lookup -----
// Output record: bits[0,4)=nib, bits[4,13)=v, bit13 = u&1; bucket = u>>1.
__device__ __forceinline__ void proc_rec(
        unsigned int w,
        const unsigned int* __restrict__ slice,
        unsigned short* __restrict__ segB, unsigned int* __restrict__ rankB,
        unsigned int* __restrict__ spillcntB, unsigned int* __restrict__ spillB) {
    unsigned int hl = w >> 18;
    unsigned int u  = (w >> 9) & 0x1FFu;
    unsigned int v  = w & 0x1FFu;
    unsigned int nib = (slice[hl >> 3] >> ((hl & 7u) * 4u)) & 0xFu;
    unsigned int bkt = u >> 1;
    unsigned int rec = ((u & 1u) << 13) | (v << 4) | nib;
    unsigned int r = atomicAdd(&rankB[bkt], 1u);            // LDS atomic
    if (r < CAPB) {
        segB[r * LROWB + bkt] = (unsigned short)rec;        // LDS write
    } else {
        unsigned int rs = atomicAdd(spillcntB, 1u);
        if (rs < SPILLCAP) spillB[rs] = (bkt << 16) | rec;
    }
}

__global__ __launch_bounds__(PBT)
void binlookup_kernel(const unsigned int* __restrict__ gsegA,
                      const unsigned short* __restrict__ cntA,
                      const unsigned int* __restrict__ sig32,
                      unsigned short* __restrict__ recs,
                      unsigned short* __restrict__ cntg,
                      const unsigned int* __restrict__ hdr,   // [0]=nspillA
                      const unsigned long long* __restrict__ spillA,
                      unsigned int* __restrict__ spillcntB,   // = hdr+1
                      unsigned int* __restrict__ spillB) {
    __shared__ unsigned int   slice[2048];                  // 8 KB sign-slice
    __shared__ unsigned short segB[CAPB * LROWB];           // 37,152 B
    __shared__ unsigned int   rankB[NBKT];                  // 1 KB
    __shared__ unsigned short cA[32];
    const int t = threadIdx.x, b = blockIdx.x;
    const int g = b / SUBS, k = b % SUBS;
    if (t < NBKT) rankB[t] = 0;
    if (t < 32)  cA[t] = cntA[g * NBLKA + k * 32 + t];
    for (int i = t; i < 2048; i += PBT) slice[i] = sig32[g * 2048 + i];
    __syncthreads();

    // 32 source segments x CAPA records, coalesced reads.
    for (int j = t; j < 32 * CAPA; j += PBT) {
        const int s = j / CAPA, r = j % CAPA;
        if (r < (int)cA[s]) {
            unsigned int w = gsegA[((size_t)(k * 32 + s) * NGRP + g) * CAPA + r];
            proc_rec(w, slice, segB, rankB, spillcntB, spillB);
        }
    }
    if (k == 0) {                                           // group's A-spills
        unsigned int ns = min(hdr[0], (unsigned int)SPILLCAP);
        for (unsigned int i2 = t; i2 < ns; i2 += PBT) {
            unsigned long long e = spillA[i2];
            if ((unsigned int)(e >> 32) == (unsigned int)g)
                proc_rec((unsigned int)e, slice, segB, rankB, spillcntB, spillB);
        }
    }
    __syncthreads();

    // Coalesced drain in histnorm's format: recs[b][bkt][CAPB] u16 (u32 pairs).
    unsigned int* gout = (unsigned int*)(recs + (size_t)b * NBKT * CAPB);
    for (int j = t; j < NBKT * CAPB / 2; j += PBT) {
        const int bkt = j / (CAPB / 2);
        const int r   = (j % (CAPB / 2)) * 2;
        unsigned int lo = segB[r * LROWB + bkt];
        unsigned int hi = segB[(r + 1) * LROWB + bkt];
        gout[j] = lo | (hi << 16);
    }
    if (t < NBKT)
        cntg[t * NBLKB + b] = (unsigned short)min(rankB[t], (unsigned int)CAPB);
}

// --------------------------------------------------------------- histnorm ---
// Parity-split: one block per OUTPUT ROW (510 blocks). Block (bkt,par)
// reads bucket bkt's records, keeps those with u&1 == par, and histograms
// only v (510 cells). Halves per-block u64 LDS-atomic work and doubles CU
// utilization vs the 255-block variant (which left half the chip idle).
__device__ __forceinline__ void hist_add_row(unsigned long long* hist,
                                             unsigned int rec, unsigned int par) {
    if ((rec >> 13) != par) return;
    unsigned int nib = rec & 0xFu;
    unsigned int v   = (rec >> 4) & 0x1FFu;
    unsigned long long add = 1ull
        | ((unsigned long long)(nib & 1u)        << 12)
        | ((unsigned long long)((nib >> 1) & 1u) << 24)
        | ((unsigned long long)((nib >> 2) & 1u) << 36)
        | ((unsigned long long)((nib >> 3) & 1u) << 48);
    atomicAdd(&hist[v], add);
}

__global__ __launch_bounds__(PHT)
void histnorm_kernel(const unsigned short* __restrict__ recs,
                     const unsigned short* __restrict__ cntg,
                     const unsigned int* __restrict__ hdr,   // [1]=nspillB
                     const unsigned int* __restrict__ spillB,
                     float* __restrict__ out) {
    __shared__ unsigned long long hist[SCALE];               // 4,080 B (one row)
    __shared__ unsigned short cl[NBLKB];
    const int t   = threadIdx.x;
    const int blk = blockIdx.x;                              // [0, 510)
    const int b   = blk >> 1;                                // bucket
    const unsigned int par = (unsigned int)(blk & 1);        // row parity
    for (int i = t; i < SCALE; i += PHT) hist[i] = 0;
    if (t < NBLKB) cl[t] = cntg[b * NBLKB + t];
    __syncthreads();

    for (int j = t; j < NBLKB * CAPB / 2; j += PHT) {
        const int s  = j / (CAPB / 2);
        const int wi = j % (CAPB / 2);
        const unsigned int* segp = (const unsigned int*)
            (recs + ((size_t)s * NBKT + b) * CAPB);
        unsigned int w = segp[wi];
        const int c = cl[s], r0 = wi * 2;
        if (r0 < c)     hist_add_row(hist, w & 0xFFFFu, par);
        if (r0 + 1 < c) hist_add_row(hist, w >> 16, par);
    }
    const unsigned int ns = min(hdr[1], (unsigned int)SPILLCAP);
    for (unsigned int i2 = t; i2 < ns; i2 += PHT) {
        unsigned int w = spillB[i2];
        if ((int)(w >> 16) == b) hist_add_row(hist, w & 0xFFFFu, par);
    }
    __syncthreads();

    // Fused normalize + store: row (2b+par) -> contiguous 16.3 KB of output.
    const size_t outbase = (size_t)(2 * b + (int)par) * SCALE * 8;  // floats
    for (int c = t; c < SCALE; c += PHT) {
        unsigned long long vv = hist[c];
        float cc = (float)(unsigned int)(vv & 0xFFFull);
        float p0 = (float)(unsigned int)((vv >> 12) & 0xFFFull);
        float p1 = (float)(unsigned int)((vv >> 24) & 0xFFFull);
        float p2 = (float)(unsigned int)((vv >> 36) & 0xFFFull);
        float p3 = (float)(unsigned int)((vv >> 48) & 0xFFFull);
        float inv = 1.0f / (cc + 1e-6f);
        float4 o0, o1;
        o0.x = p0 * inv; o0.y = (cc - p0) * inv;
        o0.z = p1 * inv; o0.w = (cc - p1) * inv;
        o1.x = p2 * inv; o1.y = (cc - p2) * inv;
        o1.z = p3 * inv; o1.w = (cc - p3) * inv;
        float4* op = (float4*)(out + outbase + (size_t)c * 8);
        op[0] = o0;
        op[1] = o1;
    }
}

// --------------------------------------------------- fallback (tiny ws) -----
__global__ void scatter_fb_kernel(const int* __restrict__ inputs,
                                  const float4* __restrict__ emb,
                                  unsigned long long* __restrict__ cnt,
                                  int n, unsigned int hmask) {
    int i = blockIdx.x * blockDim.x + threadIdx.x;
    if (i >= n) return;
    int x = inputs[3 * i], y = inputs[3 * i + 1], z = inputs[3 * i + 2];
    unsigned int h = (unsigned int)x ^ ((unsigned int)y * PRIME_Y)
                   ^ ((unsigned int)z * PRIME_Z);
    float4 e = emb[h & hmask];
    unsigned long long add = 1ull;
    if (e.x >= 0.0f) add |= 1ull << 12;
    if (e.y >= 0.0f) add |= 1ull << 24;
    if (e.z >= 0.0f) add |= 1ull << 36;
    if (e.w >= 0.0f) add |= 1ull << 48;
    int u = min(max(x, 0), SCALE - 1);
    int v = min(max(y, 0), SCALE - 1);
    atomicAdd(&cnt[u * SCALE + v], add);
}

__global__ void normalize_fb_kernel(const unsigned long long* __restrict__ cnt,
                                    float* __restrict__ out) {
    int i = blockIdx.x * blockDim.x + threadIdx.x;
    if (i >= NCELLS) return;
    unsigned long long v = cnt[i];
    float c  = (float)(unsigned int)(v & 0xFFFull);
    float p0 = (float)(unsigned int)((v >> 12) & 0xFFFull);
    float p1 = (float)(unsigned int)((v >> 24) & 0xFFFull);
    float p2 = (float)(unsigned int)((v >> 36) & 0xFFFull);
    float p3 = (float)(unsigned int)((v >> 48) & 0xFFFull);
    float inv = 1.0f / (c + 1e-6f);
    float4 o0, o1;
    o0.x = p0 * inv; o0.y = (c - p0) * inv;
    o0.z = p1 * inv; o0.w = (c - p1) * inv;
    o1.x = p2 * inv; o1.y = (c - p2) * inv;
    o1.z = p3 * inv; o1.w = (c - p3) * inv;
    float4* outv = (float4*)(out + (size_t)i * 8);
    outv[0] = o0; outv[1] = o1;
}

// ------------------------------------------------------------------ launch --
extern "C" void kernel_launch(void* const* d_in, const int* in_sizes, int n_in,
                              void* d_out, int out_size, void* d_ws, size_t ws_size,
                              hipStream_t stream) {
    const int*    inputs = (const int*)d_in[0];
    const float4* emb    = (const float4*)d_in[1];
    int n = in_sizes[0] / 3;
    unsigned int hsize = (unsigned int)(in_sizes[1] / NF);
    unsigned int hmask = hsize - 1;

    const size_t need = GSEGA_BYTES + RECS_BYTES + CNTA_BYTES + CNTG_BYTES
                      + SIGN_BYTES + HDR_BYTES + SPILLA_BYTES + SPILLB_BYTES;

    if (ws_size >= need && hsize == (1u << 19)) {
        char* w = (char*)d_ws;
        unsigned int*       gsegA   = (unsigned int*)w;            w += GSEGA_BYTES;
        unsigned short*     recs    = (unsigned short*)w;          w += RECS_BYTES;
        unsigned short*     cntA    = (unsigned short*)w;          w += CNTA_BYTES;
        unsigned short*     cntg    = (unsigned short*)w;          w += CNTG_BYTES;
        unsigned char*      signtab = (unsigned char*)w;           w += SIGN_BYTES;
        unsigned int*       hdr     = (unsigned int*)w;            w += HDR_BYTES;
        unsigned long long* spillA  = (unsigned long long*)w;      w += SPILLA_BYTES;
        unsigned int*       spillB  = (unsigned int*)w;

        signtab_kernel<<<((int)(hsize / 2) + 255) / 256, 256, 0, stream>>>(
            emb, signtab, hdr, hsize);
        hashsplit_kernel<<<NBLKA, PAT, 0, stream>>>(
            inputs, gsegA, cntA, hdr, spillA, n, hmask);
        binlookup_kernel<<<NBLKB, PBT, 0, stream>>>(
            gsegA, cntA, (const unsigned int*)signtab, recs, cntg,
            hdr, spillA, hdr + 1, spillB);
        histnorm_kernel<<<510, PHT, 0, stream>>>(
            recs, cntg, hdr, spillB, (float*)d_out);
    } else {
        unsigned long long* cnt = (unsigned long long*)d_ws;
        hipMemsetAsync(cnt, 0, (size_t)NCELLS * 8, stream);
        const int threads = 256;
        scatter_fb_kernel<<<(n + threads - 1) / threads, threads, 0, stream>>>(
            inputs, emb, cnt, n, hmask);
        normalize_fb_kernel<<<(NCELLS + threads - 1) / threads, threads, 0, stream>>>(
            cnt, (float*)d_out);
    }
}

// Round 16
// 44.745 us; speedup vs baseline: 1.0856x; 1.0856x over previous
//
#include <hip/hip_runtime.h>

// Problem constants (resolution = 512 per reference).
#define SCALE   510                // resolution - 2
#define NCELLS  (SCALE * SCALE)    // 260100
#define NF      4
#define PRIME_Y 2654435761u
#define PRIME_Z 805459861u

// Phase A: hash-partition into 32 groups (idx>>14), LDS-staged.
#define NGRP    32
#define NBLKA   512
#define CAPA    320      // per-(block,group) mean 244, +4.9 sigma
#define PAT     1024
#define SEGASTR 321      // +1 pad: bank = (g+r)%32, random g spreads

// Phase B: per-group table slice in LDS + x-bucket binning (r6 format).
#define NBKT    256      // bkt = u>>1 in [0,254]
#define NBLKB   512      // 32 groups x 16 subsets
#define SUBS    16
#define CAPB    72       // mean 30.5 (61 for bkt 254); spill path covers tails
#define PBT     1024
#define LROWB   258      // u16 stride: drain conflict-free, bin spread by bkt

#define PHT     1024
#define SPILLCAP 65536

// Workspace layout (bytes, all 256-aligned by construction):
#define GSEGA_BYTES  ((size_t)NBLKA * NGRP * CAPA * 4)     // 20,971,520
#define RECS_BYTES   ((size_t)NBLKB * NBKT * CAPB * 2)     // 18,874,368
#define CNTA_BYTES   ((size_t)NGRP * NBLKA * 2)            // 32,768
#define CNTG_BYTES   ((size_t)NBKT * NBLKB * 2)            // 262,144
#define SIGN_BYTES   ((size_t)262144)                      // 2^19 nibbles
#define HDR_BYTES    ((size_t)256)
#define SPILLA_BYTES ((size_t)SPILLCAP * 8)
#define SPILLB_BYTES ((size_t)SPILLCAP * 4)

// ---------------------------------------------------------------- signtab ---
// Pack 4 sign bits per hash entry into a nibble (2^19 entries -> 256 KB).
// Also zeroes the two spill counters.
__global__ void signtab_kernel(const float4* __restrict__ emb,
                               unsigned char* __restrict__ signtab,
                               unsigned int* __restrict__ hdr,
                               unsigned int hsize) {
    unsigned int i = blockIdx.x * blockDim.x + threadIdx.x;   // byte index
    if (i < 2) hdr[i] = 0;
    if (i * 2 >= hsize) return;
    float4 e0 = emb[2 * i + 0];
    float4 e1 = emb[2 * i + 1];
    unsigned int b = 0;
    if (e0.x >= 0.0f) b |= 1u << 0;
    if (e0.y >= 0.0f) b |= 1u << 1;
    if (e0.z >= 0.0f) b |= 1u << 2;
    if (e0.w >= 0.0f) b |= 1u << 3;
    if (e1.x >= 0.0f) b |= 1u << 4;
    if (e1.y >= 0.0f) b |= 1u << 5;
    if (e1.z >= 0.0f) b |= 1u << 6;
    if (e1.w >= 0.0f) b |= 1u << 7;
    signtab[i] = (unsigned char)b;
}

// -------------------------------------------------------- phase A: split ----
// Record: (hlow14 << 18) | (u9 << 9) | v9  — exactly 32 bits.
__device__ __forceinline__ void split_point(
        int x, int y, int z,
        unsigned int* __restrict__ segA, unsigned int* __restrict__ rankA,
        unsigned int* __restrict__ spillcnt, unsigned long long* __restrict__ spillA,
        unsigned int hmask) {
    unsigned int h = (unsigned int)x
                   ^ ((unsigned int)y * PRIME_Y)
                   ^ ((unsigned int)z * PRIME_Z);
    unsigned int idx = h & hmask;
    unsigned int g   = idx >> 14;          // 5 bits (hsize == 2^19 guarded)
    unsigned int hl  = idx & 0x3FFFu;      // 14 bits
    unsigned int u = (unsigned int)min(max(x, 0), SCALE - 1);
    unsigned int v = (unsigned int)min(max(y, 0), SCALE - 1);
    unsigned int w = (hl << 18) | (u << 9) | v;
    unsigned int r = atomicAdd(&rankA[g], 1u);              // LDS atomic
    if (r < CAPA) {
        segA[g * SEGASTR + r] = w;                          // LDS write
    } else {                                                // ~0 expected
        unsigned int rs = atomicAdd(spillcnt, 1u);
        if (rs < SPILLCAP)
            spillA[rs] = ((unsigned long long)g << 32) | w;
    }
}

__global__ __launch_bounds__(PAT)
void hashsplit_kernel(const int* __restrict__ inputs,
                      unsigned int* __restrict__ gsegA,
                      unsigned short* __restrict__ cntA,
                      unsigned int* __restrict__ hdr,
                      unsigned long long* __restrict__ spillA,
                      int n, unsigned int hmask) {
    __shared__ unsigned int segA[NGRP * SEGASTR];           // 41,088 B
    __shared__ unsigned int rankA[NGRP];
    const int t = threadIdx.x, b = blockIdx.x;
    if (t < NGRP) rankA[t] = 0;
    __syncthreads();

    const int nquad = n >> 2;
    const int qpb = (nquad + NBLKA - 1) / NBLKA;
    const int q0 = b * qpb;
    const int q1 = min(q0 + qpb, nquad);
    const int4* in4 = (const int4*)inputs;
    for (int q = q0 + t; q < q1; q += PAT) {
        int4 A = in4[3 * q + 0];
        int4 B = in4[3 * q + 1];
        int4 C = in4[3 * q + 2];
        split_point(A.x, A.y, A.z, segA, rankA, hdr, spillA, hmask);
        split_point(A.w, B.x, B.y, segA, rankA, hdr, spillA, hmask);
        split_point(B.z, B.w, C.x, segA, rankA, hdr, spillA, hmask);
        split_point(C.y, C.z, C.w, segA, rankA, hdr, spillA, hmask);
    }
    if (b == 0 && t == 0) {                                 // n%4 tail
        for (int p = nquad * 4; p < n; ++p)
            split_point(inputs[3 * p], inputs[3 * p + 1], inputs[3 * p + 2],
                        segA, rankA, hdr, spillA, hmask);
    }
    __syncthreads();

    // Coalesced drain: [g][r] -> gsegA[b][g][r].
    for (int j = t; j < NGRP * CAPA; j += PAT)
        gsegA[(size_t)b * NGRP * CAPA + j] =
            segA[(j / CAPA) * SEGASTR + (j % CAPA)];
    if (t < NGRP)
        cntA[t * NBLKA + b] = (unsigned short)min(rankA[t], (unsigned int)CAPA);
}

// ------------------------------------------------------ phase B: lookup -----
// Output record: bits[0,4)=nib, bits[4,13)=v, bit13 = u&1; bucket = u>>1.
__device__ __forceinline__ void proc_rec(
        unsigned int w,
        const unsigned int* __restrict__ slice,
        unsigned short* __restrict__ segB, unsigned int* __restrict__ rankB,
        unsigned int* __restrict__ spillcntB, unsigned int* __restrict__ spillB) {
    unsigned int hl = w >> 18;
    unsigned int u  = (w >> 9) & 0x1FFu;
    unsigned int v  = w & 0x1FFu;
    unsigned int nib = (slice[hl >> 3] >> ((hl & 7u) * 4u)) & 0xFu;
    unsigned int bkt = u >> 1;
    unsigned int rec = ((u & 1u) << 13) | (v << 4) | nib;
    unsigned int r = atomicAdd(&rankB[bkt], 1u);            // LDS atomic
    if (r < CAPB) {
        segB[r * LROWB + bkt] = (unsigned short)rec;        // LDS write
    } else {
        unsigned int rs = atomicAdd(spillcntB, 1u);
        if (rs < SPILLCAP) spillB[rs] = (bkt << 16) | rec;
    }
}

__global__ __launch_bounds__(PBT)
void binlookup_kernel(const unsigned int* __restrict__ gsegA,
                      const unsigned short* __restrict__ cntA,
                      const unsigned int* __restrict__ sig32,
                      unsigned short* __restrict__ recs,
                      unsigned short* __restrict__ cntg,
                      const unsigned int* __restrict__ hdr,   // [0]=nspillA
                      const unsigned long long* __restrict__ spillA,
                      unsigned int* __restrict__ spillcntB,   // = hdr+1
                      unsigned int* __restrict__ spillB) {
    __shared__ unsigned int   slice[2048];                  // 8 KB sign-slice
    __shared__ unsigned short segB[CAPB * LROWB];           // 37,152 B
    __shared__ unsigned int   rankB[NBKT];                  // 1 KB
    __shared__ unsigned short cA[32];
    const int t = threadIdx.x, b = blockIdx.x;
    const int g = b / SUBS, k = b % SUBS;
    if (t < NBKT) rankB[t] = 0;
    if (t < 32)  cA[t] = cntA[g * NBLKA + k * 32 + t];
    for (int i = t; i < 2048; i += PBT) slice[i] = sig32[g * 2048 + i];
    __syncthreads();

    // 32 source segments x CAPA records, coalesced reads.
    for (int j = t; j < 32 * CAPA; j += PBT) {
        const int s = j / CAPA, r = j % CAPA;
        if (r < (int)cA[s]) {
            unsigned int w = gsegA[((size_t)(k * 32 + s) * NGRP + g) * CAPA + r];
            proc_rec(w, slice, segB, rankB, spillcntB, spillB);
        }
    }
    if (k == 0) {                                           // group's A-spills
        unsigned int ns = min(hdr[0], (unsigned int)SPILLCAP);
        for (unsigned int i2 = t; i2 < ns; i2 += PBT) {
            unsigned long long e = spillA[i2];
            if ((unsigned int)(e >> 32) == (unsigned int)g)
                proc_rec((unsigned int)e, slice, segB, rankB, spillcntB, spillB);
        }
    }
    __syncthreads();

    // Coalesced drain in histnorm's format: recs[b][bkt][CAPB] u16 (u32 pairs).
    unsigned int* gout = (unsigned int*)(recs + (size_t)b * NBKT * CAPB);
    for (int j = t; j < NBKT * CAPB / 2; j += PBT) {
        const int bkt = j / (CAPB / 2);
        const int r   = (j % (CAPB / 2)) * 2;
        unsigned int lo = segB[r * LROWB + bkt];
        unsigned int hi = segB[(r + 1) * LROWB + bkt];
        gout[j] = lo | (hi << 16);
    }
    if (t < NBKT)
        cntg[t * NBLKB + b] = (unsigned short)min(rankB[t], (unsigned int)CAPB);
}

// --------------------------------------------------------------- histnorm ---
__device__ __forceinline__ void hist_add(unsigned long long* hist,
                                         unsigned int rec) {
    unsigned int nib = rec & 0xFu;
    unsigned int v   = (rec >> 4) & 0x1FFu;
    unsigned int ul  = rec >> 13;
    unsigned long long add = 1ull
        | ((unsigned long long)(nib & 1u)        << 12)
        | ((unsigned long long)((nib >> 1) & 1u) << 24)
        | ((unsigned long long)((nib >> 2) & 1u) << 36)
        | ((unsigned long long)((nib >> 3) & 1u) << 48);
    atomicAdd(&hist[ul * SCALE + v], add);
}

// 255 blocks: block b handles bucket b -> grid rows {2b, 2b+1}.
__global__ __launch_bounds__(PHT)
void histnorm_kernel(const unsigned short* __restrict__ recs,
                     const unsigned short* __restrict__ cntg,
                     const unsigned int* __restrict__ hdr,   // [1]=nspillB
                     const unsigned int* __restrict__ spillB,
                     float* __restrict__ out) {
    __shared__ unsigned long long hist[2 * SCALE];           // 8.2 KB
    __shared__ unsigned short cl[NBLKB];
    const int t = threadIdx.x, b = blockIdx.x;               // b in [0,255)
    for (int i = t; i < 2 * SCALE; i += PHT) hist[i] = 0;
    if (t < NBLKB) cl[t] = cntg[b * NBLKB + t];
    __syncthreads();

    for (int j = t; j < NBLKB * CAPB / 2; j += PHT) {
        const int s  = j / (CAPB / 2);
        const int wi = j % (CAPB / 2);
        const unsigned int* segp = (const unsigned int*)
            (recs + ((size_t)s * NBKT + b) * CAPB);
        unsigned int w = segp[wi];
        const int c = cl[s], r0 = wi * 2;
        if (r0 < c)     hist_add(hist, w & 0xFFFFu);
        if (r0 + 1 < c) hist_add(hist, w >> 16);
    }
    const unsigned int ns = min(hdr[1], (unsigned int)SPILLCAP);
    for (unsigned int i2 = t; i2 < ns; i2 += PHT) {
        unsigned int w = spillB[i2];
        if ((int)(w >> 16) == b) hist_add(hist, w & 0xFFFFu);
    }
    __syncthreads();

    const size_t outbase = (size_t)(2 * b) * SCALE * 8;     // floats
    for (int c = t; c < 2 * SCALE; c += PHT) {
        unsigned long long vv = hist[c];
        float cc = (float)(unsigned int)(vv & 0xFFFull);
        float p0 = (float)(unsigned int)((vv >> 12) & 0xFFFull);
        float p1 = (float)(unsigned int)((vv >> 24) & 0xFFFull);
        float p2 = (float)(unsigned int)((vv >> 36) & 0xFFFull);
        float p3 = (float)(unsigned int)((vv >> 48) & 0xFFFull);
        float inv = 1.0f / (cc + 1e-6f);
        float4 o0, o1;
        o0.x = p0 * inv; o0.y = (cc - p0) * inv;
        o0.z = p1 * inv; o0.w = (cc - p1) * inv;
        o1.x = p2 * inv; o1.y = (cc - p2) * inv;
        o1.z = p3 * inv; o1.w = (cc - p3) * inv;
        float4* op = (float4*)(out + outbase + (size_t)c * 8);
        op[0] = o0;
        op[1] = o1;
    }
}

// --------------------------------------------------- fallback (tiny ws) -----
__global__ void scatter_fb_kernel(const int* __restrict__ inputs,
                                  const float4* __restrict__ emb,
                                  unsigned long long* __restrict__ cnt,
                                  int n, unsigned int hmask) {
    int i = blockIdx.x * blockDim.x + threadIdx.x;
    if (i >= n) return;
    int x = inputs[3 * i], y = inputs[3 * i + 1], z = inputs[3 * i + 2];
    unsigned int h = (unsigned int)x ^ ((unsigned int)y * PRIME_Y)
                   ^ ((unsigned int)z * PRIME_Z);
    float4 e = emb[h & hmask];
    unsigned long long add = 1ull;
    if (e.x >= 0.0f) add |= 1ull << 12;
    if (e.y >= 0.0f) add |= 1ull << 24;
    if (e.z >= 0.0f) add |= 1ull << 36;
    if (e.w >= 0.0f) add |= 1ull << 48;
    int u = min(max(x, 0), SCALE - 1);
    int v = min(max(y, 0), SCALE - 1);
    atomicAdd(&cnt[u * SCALE + v], add);
}

__global__ void normalize_fb_kernel(const unsigned long long* __restrict__ cnt,
                                    float* __restrict__ out) {
    int i = blockIdx.x * blockDim.x + threadIdx.x;
    if (i >= NCELLS) return;
    unsigned long long v = cnt[i];
    float c  = (float)(unsigned int)(v & 0xFFFull);
    float p0 = (float)(unsigned int)((v >> 12) & 0xFFFull);
    float p1 = (float)(unsigned int)((v >> 24) & 0xFFFull);
    float p2 = (float)(unsigned int)((v >> 36) & 0xFFFull);
    float p3 = (float)(unsigned int)((v >> 48) & 0xFFFull);
    float inv = 1.0f / (c + 1e-6f);
    float4 o0, o1;
    o0.x = p0 * inv; o0.y = (c - p0) * inv;
    o0.z = p1 * inv; o0.w = (c - p1) * inv;
    o1.x = p2 * inv; o1.y = (c - p2) * inv;
    o1.z = p3 * inv; o1.w = (c - p3) * inv;
    float4* outv = (float4*)(out + (size_t)i * 8);
    outv[0] = o0; outv[1] = o1;
}

// ------------------------------------------------------------------ launch --
extern "C" void kernel_launch(void* const* d_in, const int* in_sizes, int n_in,
                              void* d_out, int out_size, void* d_ws, size_t ws_size,
                              hipStream_t stream) {
    const int*    inputs = (const int*)d_in[0];
    const float4* emb    = (const float4*)d_in[1];
    int n = in_sizes[0] / 3;
    unsigned int hsize = (unsigned int)(in_sizes[1] / NF);
    unsigned int hmask = hsize - 1;

    const size_t need = GSEGA_BYTES + RECS_BYTES + CNTA_BYTES + CNTG_BYTES
                      + SIGN_BYTES + HDR_BYTES + SPILLA_BYTES + SPILLB_BYTES;

    if (ws_size >= need && hsize == (1u << 19)) {
        char* w = (char*)d_ws;
        unsigned int*       gsegA   = (unsigned int*)w;            w += GSEGA_BYTES;
        unsigned short*     recs    = (unsigned short*)w;          w += RECS_BYTES;
        unsigned short*     cntA    = (unsigned short*)w;          w += CNTA_BYTES;
        unsigned short*     cntg    = (unsigned short*)w;          w += CNTG_BYTES;
        unsigned char*      signtab = (unsigned char*)w;           w += SIGN_BYTES;
        unsigned int*       hdr     = (unsigned int*)w;            w += HDR_BYTES;
        unsigned long long* spillA  = (unsigned long long*)w;      w += SPILLA_BYTES;
        unsigned int*       spillB  = (unsigned int*)w;

        signtab_kernel<<<((int)(hsize / 2) + 255) / 256, 256, 0, stream>>>(
            emb, signtab, hdr, hsize);
        hashsplit_kernel<<<NBLKA, PAT, 0, stream>>>(
            inputs, gsegA, cntA, hdr, spillA, n, hmask);
        binlookup_kernel<<<NBLKB, PBT, 0, stream>>>(
            gsegA, cntA, (const unsigned int*)signtab, recs, cntg,
            hdr, spillA, hdr + 1, spillB);
        histnorm_kernel<<<255, PHT, 0, stream>>>(
            recs, cntg, hdr, spillB, (float*)d_out);
    } else {
        unsigned long long* cnt = (unsigned long long*)d_ws;
        hipMemsetAsync(cnt, 0, (size_t)NCELLS * 8, stream);
        const int threads = 256;
        scatter_fb_kernel<<<(n + threads - 1) / threads, threads, 0, stream>>>(
            inputs, emb, cnt, n, hmask);
        normalize_fb_kernel<<<(NCELLS + threads - 1) / threads, threads, 0, stream>>>(
            cnt, (float*)d_out);
    }
}